// Round 1
// 617.436 us; speedup vs baseline: 1.0241x; 1.0241x over previous
//
#include <hip/hip_runtime.h>
#include <stdint.h>

#define BB 256      // batch
#define TT 200      // timesteps
#define INN 1568    // inputs
#define OO 100      // outputs
#define PAIRS 784   // INN/2
#define NHALF 12800 // (BB*OO)/2

typedef unsigned long long u64;
typedef __attribute__((ext_vector_type(4))) int v4i;  // clang-native for NT loads

// ---------------- threefry2x32 (JAX-compatible) ----------------
__device__ __forceinline__ void tf_round(uint32_t& x0, uint32_t& x1, int r) {
    x0 += x1;
    x1 = (x1 << r) | (x1 >> (32 - r));
    x1 ^= x0;
}

__device__ __forceinline__ void threefry(uint32_t k0, uint32_t k1,
                                         uint32_t x0, uint32_t x1,
                                         uint32_t& o0, uint32_t& o1) {
    uint32_t k2 = k0 ^ k1 ^ 0x1BD11BDAu;
    x0 += k0; x1 += k1;
    tf_round(x0,x1,13); tf_round(x0,x1,15); tf_round(x0,x1,26); tf_round(x0,x1,6);
    x0 += k1; x1 += k2 + 1u;
    tf_round(x0,x1,17); tf_round(x0,x1,29); tf_round(x0,x1,16); tf_round(x0,x1,24);
    x0 += k2; x1 += k0 + 2u;
    tf_round(x0,x1,13); tf_round(x0,x1,15); tf_round(x0,x1,26); tf_round(x0,x1,6);
    x0 += k0; x1 += k1 + 3u;
    tf_round(x0,x1,17); tf_round(x0,x1,29); tf_round(x0,x1,16); tf_round(x0,x1,24);
    x0 += k1; x1 += k2 + 4u;
    tf_round(x0,x1,13); tf_round(x0,x1,15); tf_round(x0,x1,26); tf_round(x0,x1,6);
    o0 = x0 + k2; o1 = x1 + k0 + 5u;
}

// K1: fused winners + x->bit pack, 64-thread blocks. [unchanged — proven]
__global__ __launch_bounds__(64) void k_winbit(const int* __restrict__ x,
                                               uint8_t* __restrict__ widx,
                                               u64* __restrict__ bitB) {
    if (blockIdx.x < 800) {
        int idx = blockIdx.x * 64 + threadIdx.x;   // < TT*BB = 51200
        int t = idx >> 8, b = idx & 255;
        uint32_t fk0, fk1;
        threefry(0u, 42u, 0u, (uint32_t)t, fk0, fk1);   // fold_in(key(42), t)
        uint32_t bestkey = 0u;
        int bo = 0;
        int nbase = b * OO;
        for (int o = 0; o < OO; ++o) {
            uint32_t n = (uint32_t)(nbase + o);
            uint32_t lo = (n < NHALF) ? n : n - NHALF;
            uint32_t v0, v1;
            threefry(fk0, fk1, lo, lo + NHALF, v0, v1);
            uint32_t bits = (n < NHALF) ? v0 : v1;
            uint32_t key = bits >> 9;       // monotone proxy for gumbel
            if (key > bestkey) { bestkey = key; bo = o; }
        }
        widx[idx] = (uint8_t)bo;
    } else {
        int idx = (blockIdx.x - 800) * 64 + threadIdx.x; // < 4*TT*392 = 313600
        int wb = idx / (TT * 392);
        int r = idx - wb * (TT * 392);
        int t = r / 392;
        int ig = r - t * 392;                 // group of 4 inputs
        const v4i* xp = (const v4i*)x;
        u64 m0 = 0, m1 = 0, m2 = 0, m3 = 0;
        for (int j = 0; j < 64; ++j) {
            int b = wb * 64 + j;
            v4i v = __builtin_nontemporal_load(&xp[((size_t)b * TT + t) * 392 + ig]);
            u64 bit = 1ull << j;
            if (v.x) m0 |= bit;
            if (v.y) m1 |= bit;
            if (v.z) m2 |= bit;
            if (v.w) m3 |= bit;
        }
        u64* dst = bitB + ((size_t)(t * 4 + wb)) * INN + 4 * ig;
        dst[0] = m0; dst[1] = m1; dst[2] = m2; dst[3] = m3;
    }
}

// K2: fused firstwin + winpost. [unchanged — proven]
__global__ __launch_bounds__(256) void k_fwpost(const uint8_t* __restrict__ widx,
                                                u64* __restrict__ winbits,
                                                u64* __restrict__ postbits,
                                                uint32_t* __restrict__ cnt) {
    __shared__ uint32_t wl32[TT * 65];
    __shared__ int fwl[BB];
    int o = blockIdx.x;
    int tid = threadIdx.x;
    const uint32_t* wsrc = (const uint32_t*)widx;
    for (int g = tid; g < TT * 64; g += 256) {
        int t = g >> 6, w = g & 63;
        wl32[t * 65 + w] = wsrc[g];
    }
    __syncthreads();
    if (tid < 64) {
        int f0 = 255, f1 = 255, f2 = 255, f3 = 255;
        for (int t = 0; t < TT; ++t) {
            uint32_t w4 = wl32[t * 65 + tid];
            if (((w4      ) & 255u) == (uint32_t)o && f0 == 255) f0 = t;
            if (((w4 >>  8) & 255u) == (uint32_t)o && f1 == 255) f1 = t;
            if (((w4 >> 16) & 255u) == (uint32_t)o && f2 == 255) f2 = t;
            if (((w4 >> 24) & 255u) == (uint32_t)o && f3 == 255) f3 = t;
        }
        fwl[4 * tid + 0] = f0; fwl[4 * tid + 1] = f1;
        fwl[4 * tid + 2] = f2; fwl[4 * tid + 3] = f3;
    }
    __syncthreads();
    if (tid < TT) {
        int t = tid;
        u64 wbA[4], pbA[4];
        uint32_t c = 0;
        #pragma unroll
        for (int k = 0; k < 4; ++k) {
            u64 wacc = 0, pacc = 0;
            for (int q2 = 0; q2 < 16; ++q2) {
                uint32_t w4 = wl32[t * 65 + k * 16 + q2];
                #pragma unroll
                for (int j = 0; j < 4; ++j) {
                    int bl = q2 * 4 + j;
                    bool win = (((w4 >> (8 * j)) & 255u) == (uint32_t)o);
                    c += win ? 1u : 0u;
                    bool post = (fwl[k * 64 + q2 * 4 + j] < t) && !win;
                    u64 bit = 1ull << bl;
                    if (win)  wacc |= bit;
                    if (post) pacc |= bit;
                }
            }
            wbA[k] = wacc; pbA[k] = pacc;
        }
        size_t base = (size_t)(t * OO + o) * 4;
        #pragma unroll
        for (int k = 0; k < 4; ++k) {
            winbits[base + k] = wbA[k];
            postbits[base + k] = pbA[k];
        }
        cnt[t * OO + o] = c;
    }
}

// K3: FUSED popc + chains + prior. Replaces the CT-chunked k_popcW/k_chainsPrior
// loop (50x2 serialized tiny launches at CT=4 were ~80% of runtime).
// Block = 16 pairs x 20 outputs (320 thr, 5 waves). Per t: 128 threads recompute
// the 11-row OR window for the block's 16 pairs into LDS (OR-idempotent row-0
// clamp makes it branch-free for t<10); 160 threads stage win/post masks;
// 20 threads stage cnt. All 320 run their (a,b2) chains from LDS with EXACT
// popcounts (no 255 saturation). Double-buffered LDS, loads issued before the
// chain fp-work and written after (T14 split), one barrier per t.
// No `packed` intermediate: -62.7 MB write, -62.7 MB read, ws need = base only.
#define PBLK 16
#define OBLK 20
#define FTHR 320
#define ROWSTRIDE (4 * INN)   // u64 elements per t-row of bitB

__global__ __launch_bounds__(FTHR) void k_fused(
        const float* __restrict__ L0,
        const float* __restrict__ p0arr,
        const u64* __restrict__ bitB,
        const u64* __restrict__ winbits,
        const u64* __restrict__ postbits,
        const uint32_t* __restrict__ cnt,
        float* __restrict__ outL,
        float* __restrict__ outp) {
    // ---- prior chain: single extra block, runs concurrently ----
    if (blockIdx.x == 49) {
        if (blockIdx.y != 0) return;
        int l = threadIdx.x;
        if (l >= 64) return;
        bool has2 = (l + 64) < OO;
        float pa = p0arr[l];
        float pb = has2 ? p0arr[l + 64] : -1e30f;
        auto normalize = [&]() {
            pa = fminf(fmaxf(pa, -5.0f), 0.0f);
            if (has2) pb = fminf(fmaxf(pb, -5.0f), 0.0f);
            float mx = has2 ? fmaxf(pa, pb) : pa;
            #pragma unroll
            for (int s = 32; s > 0; s >>= 1) mx = fmaxf(mx, __shfl_xor(mx, s, 64));
            float sm = expf(pa - mx) + (has2 ? expf(pb - mx) : 0.0f);
            #pragma unroll
            for (int s = 32; s > 0; s >>= 1) sm += __shfl_xor(sm, s, 64);
            float lse = logf(sm) + mx;
            pa -= lse;
            if (has2) pb -= lse;
        };
        normalize();
        for (int t = 0; t < TT; ++t) {
            float eta = 0.001f / (float)(t + 1);
            float wma = (float)cnt[t * OO + l] * (1.0f / 256.0f);
            pa += eta * ((-5.0f * pa - 1.0f) * wma - (1.0f - wma));
            if (has2) {
                float wmb = (float)cnt[t * OO + l + 64] * (1.0f / 256.0f);
                pb += eta * ((-5.0f * pb - 1.0f) * wmb - (1.0f - wmb));
            }
            normalize();
        }
        outp[l] = pa;
        if (has2) outp[l + 64] = pb;
        return;
    }

    // ---- weight chains, fused with on-the-fly window popc ----
    // stride 10 u64 per pair row: 80 B => 16-B aligned b128 reads, 2-way banks (free)
    __shared__ u64 potL[2][PBLK * 10];
    __shared__ u64 ltpL[2][PBLK * 10];
    __shared__ u64 winL[2][OBLK * 4];
    __shared__ u64 postL[2][OBLK * 4];
    __shared__ float cntL[2][OBLK];

    int tid = threadIdx.x;
    int p0 = blockIdx.x * PBLK;     // blockIdx.x in 0..48
    int o0 = blockIdx.y * OBLK;     // blockIdx.y in 0..4
    int pl = tid & 15;              // pair within block
    int ol = tid >> 4;              // 0..19: output within block; for tid<128 doubles as window k
    int o  = o0 + ol;
    int i0 = p0 + pl;
    int i1 = i0 + PAIRS;

    // window column for tid<128: k = ol (0..7); k&3 = wb, k>>2 selects i0/i1 half
    const u64* colbase = bitB + (size_t)(ol & 3) * INN
                       + ((ol < 8) ? (size_t)(p0 + pl + (ol >> 2) * PAIRS) : 0);
    int s  = tid - 128;             // staging role for tid in [128,288)
    int ols = s >> 3, js = s & 7;

    // ---- prologue: build buffer 0 for t=0 ----
    if (tid < 128) {
        u64 acc = 0, r0 = 0;
        #pragma unroll
        for (int ii = 0; ii < 11; ++ii) {
            int tt = ii - 10; tt = (tt < 0) ? 0 : tt;   // all clamp to row 0: pot(0)=row0
            u64 v = colbase[(size_t)tt * ROWSTRIDE];
            if (ii == 0) r0 = v; else acc |= v;
        }
        potL[0][pl * 10 + ol] = acc;
        ltpL[0][pl * 10 + ol] = acc | r0;
    } else if (tid < 288) {
        size_t base = (size_t)(o0 + ols) * 4;           // t=0
        if (js < 4) winL[0][ols * 4 + js] = winbits[base + js];
        else        postL[0][ols * 4 + js - 4] = postbits[base + js - 4];
    } else if (tid < 308) {
        cntL[0][tid - 288] = (float)cnt[o0 + (tid - 288)];
    }

    // chain init (== old K4 first=1 path)
    float a  = L0[(size_t)i0 * OO + o];
    float b2 = L0[(size_t)i1 * OO + o];
    a  = fminf(fmaxf(a,  -5.0f), 0.0f);
    b2 = fminf(fmaxf(b2, -5.0f), 0.0f);
    {
        float m = fmaxf(a, b2), mn = fminf(a, b2);
        float lse = __logf(1.0f + __expf(mn - m)) + m;
        a -= lse; b2 -= lse;
    }
    __syncthreads();

    for (int t = 0; t < TT; ++t) {
        int cur = t & 1, nxt = cur ^ 1;
        bool pre = (t + 1 < TT);
        // -- issue t+1 loads early (latency hides under the chain fp work) --
        u64 wv[11];
        u64 stg = 0; float cstg = 0.0f;
        if (pre) {
            if (tid < 128) {
                int tb = t + 1 - 10;
                #pragma unroll
                for (int ii = 0; ii < 11; ++ii) {
                    int tt = tb + ii; tt = (tt < 0) ? 0 : tt;  // OR-idempotent clamp
                    wv[ii] = colbase[(size_t)tt * ROWSTRIDE];
                }
            } else if (tid < 288) {
                size_t base = (size_t)((t + 1) * OO + o0 + ols) * 4;
                stg = (js < 4) ? winbits[base + js] : postbits[base + js - 4];
            } else if (tid < 308) {
                cstg = (float)cnt[(t + 1) * OO + o0 + (tid - 288)];
            }
        }
        // -- chain update from buf[cur] --
        u64 W0 = winL[cur][ol * 4 + 0], W1 = winL[cur][ol * 4 + 1];
        u64 W2 = winL[cur][ol * 4 + 2], W3 = winL[cur][ol * 4 + 3];
        u64 S0 = postL[cur][ol * 4 + 0], S1 = postL[cur][ol * 4 + 1];
        u64 S2 = postL[cur][ol * 4 + 2], S3 = postL[cur][ol * 4 + 3];
        const u64* Pp = &potL[cur][pl * 10];
        const u64* Lp = &ltpL[cur][pl * 10];
        uint32_t lt0 = __popcll(Lp[0] & W0) + __popcll(Lp[1] & W1)
                     + __popcll(Lp[2] & W2) + __popcll(Lp[3] & W3);
        uint32_t lt1 = __popcll(Lp[4] & W0) + __popcll(Lp[5] & W1)
                     + __popcll(Lp[6] & W2) + __popcll(Lp[7] & W3);
        uint32_t pp0 = __popcll(Pp[0] & S0) + __popcll(Pp[1] & S1)
                     + __popcll(Pp[2] & S2) + __popcll(Pp[3] & S3);
        uint32_t pp1 = __popcll(Pp[4] & S0) + __popcll(Pp[5] & S1)
                     + __popcll(Pp[6] & S2) + __popcll(Pp[7] & S3);
        float cwin = cntL[cur][ol];
        float lt0f = (float)lt0, lt1f = (float)lt1;
        float pp0f = (float)pp0, pp1f = (float)pp1;
        float eta = 0.001f / (float)(t + 1);
        float dw0 = (5.0f * __expf(-a)  - 1.0f) * (lt0f * (1.0f/256.0f))
                  + (cwin - lt0f - pp0f) * (1.0f/256.0f);
        float dw1 = (5.0f * __expf(-b2) - 1.0f) * (lt1f * (1.0f/256.0f))
                  + (cwin - lt1f - pp1f) * (1.0f/256.0f);
        a  += eta * dw0;
        b2 += eta * dw1;
        a  = fminf(fmaxf(a,  -5.0f), 0.0f);
        b2 = fminf(fmaxf(b2, -5.0f), 0.0f);
        float m = fmaxf(a, b2), mn = fminf(a, b2);
        float lse = __logf(1.0f + __expf(mn - m)) + m;
        a -= lse; b2 -= lse;
        // -- write prefetched t+1 data into buf[nxt] --
        if (pre) {
            if (tid < 128) {
                u64 acc = wv[1] | wv[2] | wv[3] | wv[4] | wv[5]
                        | wv[6] | wv[7] | wv[8] | wv[9] | wv[10];
                potL[nxt][pl * 10 + ol] = acc;
                ltpL[nxt][pl * 10 + ol] = acc | wv[0];
            } else if (tid < 288) {
                if (js < 4) winL[nxt][ols * 4 + js] = stg;
                else        postL[nxt][ols * 4 + js - 4] = stg;
            } else if (tid < 308) {
                cntL[nxt][tid - 288] = cstg;
            }
        }
        __syncthreads();
    }
    outL[(size_t)i0 * OO + o] = a;
    outL[(size_t)i1 * OO + o] = b2;
}

extern "C" void kernel_launch(void* const* d_in, const int* in_sizes, int n_in,
                              void* d_out, int out_size, void* d_ws, size_t ws_size,
                              hipStream_t stream) {
    const int*   x  = (const int*)d_in[0];
    const float* L0 = (const float*)d_in[1];
    const float* p0 = (const float*)d_in[2];
    float* out = (float*)d_out;

    char* ws = (char*)d_ws;
    size_t off = 0;
    auto alloc = [&](size_t bytes) -> void* {
        off = (off + 255) & ~(size_t)255;
        void* p = ws + off;
        off += bytes;
        return p;
    };
    uint8_t*  widx     = (uint8_t*) alloc((size_t)TT * BB);
    uint32_t* cnt      = (uint32_t*)alloc((size_t)TT * OO * 4);
    u64*      winbits  = (u64*)     alloc((size_t)TT * OO * 4 * 8);
    u64*      postbits = (u64*)     alloc((size_t)TT * OO * 4 * 8);
    u64*      bitB     = (u64*)     alloc((size_t)TT * 4 * INN * 8);
    // total ≈ 11.45 MB — no packed intermediate, no CT chunk loop.
    (void)ws_size;

    hipLaunchKernelGGL(k_winbit, dim3(800 + 4900), dim3(64), 0, stream, x, widx, bitB);
    hipLaunchKernelGGL(k_fwpost, dim3(OO), dim3(256), 0, stream,
                       widx, winbits, postbits, cnt);
    hipLaunchKernelGGL(k_fused, dim3(50, 5), dim3(FTHR), 0, stream,
                       L0, p0, bitB, winbits, postbits, cnt,
                       out, out + (size_t)INN * OO);
}

// Round 2
// 611.581 us; speedup vs baseline: 1.0339x; 1.0096x over previous
//
#include <hip/hip_runtime.h>
#include <stdint.h>

#define BB 256      // batch
#define TT 200      // timesteps
#define INN 1568    // inputs
#define OO 100      // outputs
#define PAIRS 784   // INN/2
#define NHALF 12800 // (BB*OO)/2

typedef unsigned long long u64;
typedef __attribute__((ext_vector_type(4))) int v4i;  // clang-native for NT loads

// async global->LDS direct copy (16 B per lane); dest = wave-uniform base + lane*16
typedef const __attribute__((address_space(1))) uint32_t* gas_p;
typedef __attribute__((address_space(3))) uint32_t* las_p;
#define GLD16(g, l) __builtin_amdgcn_global_load_lds((gas_p)(g), (las_p)(l), 16, 0, 0)

// ---------------- threefry2x32 (JAX-compatible) ----------------
__device__ __forceinline__ void tf_round(uint32_t& x0, uint32_t& x1, int r) {
    x0 += x1;
    x1 = (x1 << r) | (x1 >> (32 - r));
    x1 ^= x0;
}

__device__ __forceinline__ void threefry(uint32_t k0, uint32_t k1,
                                         uint32_t x0, uint32_t x1,
                                         uint32_t& o0, uint32_t& o1) {
    uint32_t k2 = k0 ^ k1 ^ 0x1BD11BDAu;
    x0 += k0; x1 += k1;
    tf_round(x0,x1,13); tf_round(x0,x1,15); tf_round(x0,x1,26); tf_round(x0,x1,6);
    x0 += k1; x1 += k2 + 1u;
    tf_round(x0,x1,17); tf_round(x0,x1,29); tf_round(x0,x1,16); tf_round(x0,x1,24);
    x0 += k2; x1 += k0 + 2u;
    tf_round(x0,x1,13); tf_round(x0,x1,15); tf_round(x0,x1,26); tf_round(x0,x1,6);
    x0 += k0; x1 += k1 + 3u;
    tf_round(x0,x1,17); tf_round(x0,x1,29); tf_round(x0,x1,16); tf_round(x0,x1,24);
    x0 += k1; x1 += k2 + 4u;
    tf_round(x0,x1,13); tf_round(x0,x1,15); tf_round(x0,x1,26); tf_round(x0,x1,6);
    o0 = x0 + k2; o1 = x1 + k0 + 5u;
}

// K1: winners + page-local register-accumulated bitpack.
// Pack half: block = (wb, 2 timesteps). Thread owns fixed column positions and
// accumulates 64-bit batch masks in registers across the b-loop; each b-iteration
// reads a CONTIGUOUS 12.5 KB chunk of one batch slab (page-sequential, coalesced),
// vs the old 1 KB-per-page-visit scatter. Zero LDS, bit-set via uniform-b cndmask.
__global__ __launch_bounds__(256) void k_winbit(const int* __restrict__ x,
                                                uint8_t* __restrict__ widx,
                                                u64* __restrict__ bitB) {
    int tid = threadIdx.x;
    if (blockIdx.x < 200) {            // winner half: 200*256 = TT*BB exactly
        int idx = blockIdx.x * 256 + tid;
        int t = idx >> 8, b = idx & 255;
        uint32_t fk0, fk1;
        threefry(0u, 42u, 0u, (uint32_t)t, fk0, fk1);   // fold_in(key(42), t)
        uint32_t bestkey = 0u;
        int bo = 0;
        int nbase = b * OO;
        for (int o = 0; o < OO; ++o) {
            uint32_t n = (uint32_t)(nbase + o);
            uint32_t lo = (n < NHALF) ? n : n - NHALF;
            uint32_t v0, v1;
            threefry(fk0, fk1, lo, lo + NHALF, v0, v1);
            uint32_t bits = (n < NHALF) ? v0 : v1;
            uint32_t key = bits >> 9;       // monotone proxy for gumbel
            if (key > bestkey) { bestkey = key; bo = o; }
        }
        widx[idx] = (uint8_t)bo;
        return;
    }
    // ---- pack half: 400 blocks = 4 wb x 100 t-chunks (2 t each) ----
    int pb = blockIdx.x - 200;
    int wb = pb / 100;
    int t0 = (pb - wb * 100) * 2;
    const v4i* xp = (const v4i*)x;
    u64 acc[4][4];
    #pragma unroll
    for (int q = 0; q < 4; ++q)
        #pragma unroll
        for (int c = 0; c < 4; ++c) acc[q][c] = 0;
    bool x4 = (tid < 16);              // 784 = 3*256 + 16
    for (int bl = 0; bl < 64; ++bl) {
        size_t base = ((size_t)((wb * 64 + bl) * TT + t0)) * 392;
        u64 bit = 1ull << bl;          // uniform across lanes (SGPR)
        #pragma unroll
        for (int q = 0; q < 3; ++q) {
            v4i v = __builtin_nontemporal_load(&xp[base + tid + q * 256]);
            if (v.x) acc[q][0] |= bit;
            if (v.y) acc[q][1] |= bit;
            if (v.z) acc[q][2] |= bit;
            if (v.w) acc[q][3] |= bit;
        }
        if (x4) {
            v4i v = __builtin_nontemporal_load(&xp[base + tid + 768]);
            if (v.x) acc[3][0] |= bit;
            if (v.y) acc[3][1] |= bit;
            if (v.z) acc[3][2] |= bit;
            if (v.w) acc[3][3] |= bit;
        }
    }
    #pragma unroll
    for (int q = 0; q < 4; ++q) {
        if (q == 3 && !x4) continue;
        int p = tid + q * 256;         // p < 784
        int tp = (p >= 392) ? 1 : 0;
        int iq = p - tp * 392;
        u64* dst = bitB + ((size_t)((t0 + tp) * 4 + wb)) * INN + iq * 4;
        dst[0] = acc[q][0]; dst[1] = acc[q][1];
        dst[2] = acc[q][2]; dst[3] = acc[q][3];
    }
}

// K2: fused firstwin + winpost. [unchanged — proven]
__global__ __launch_bounds__(256) void k_fwpost(const uint8_t* __restrict__ widx,
                                                u64* __restrict__ winbits,
                                                u64* __restrict__ postbits,
                                                uint32_t* __restrict__ cnt) {
    __shared__ uint32_t wl32[TT * 65];
    __shared__ int fwl[BB];
    int o = blockIdx.x;
    int tid = threadIdx.x;
    const uint32_t* wsrc = (const uint32_t*)widx;
    for (int g = tid; g < TT * 64; g += 256) {
        int t = g >> 6, w = g & 63;
        wl32[t * 65 + w] = wsrc[g];
    }
    __syncthreads();
    if (tid < 64) {
        int f0 = 255, f1 = 255, f2 = 255, f3 = 255;
        for (int t = 0; t < TT; ++t) {
            uint32_t w4 = wl32[t * 65 + tid];
            if (((w4      ) & 255u) == (uint32_t)o && f0 == 255) f0 = t;
            if (((w4 >>  8) & 255u) == (uint32_t)o && f1 == 255) f1 = t;
            if (((w4 >> 16) & 255u) == (uint32_t)o && f2 == 255) f2 = t;
            if (((w4 >> 24) & 255u) == (uint32_t)o && f3 == 255) f3 = t;
        }
        fwl[4 * tid + 0] = f0; fwl[4 * tid + 1] = f1;
        fwl[4 * tid + 2] = f2; fwl[4 * tid + 3] = f3;
    }
    __syncthreads();
    if (tid < TT) {
        int t = tid;
        u64 wbA[4], pbA[4];
        uint32_t c = 0;
        #pragma unroll
        for (int k = 0; k < 4; ++k) {
            u64 wacc = 0, pacc = 0;
            for (int q2 = 0; q2 < 16; ++q2) {
                uint32_t w4 = wl32[t * 65 + k * 16 + q2];
                #pragma unroll
                for (int j = 0; j < 4; ++j) {
                    int bl = q2 * 4 + j;
                    bool win = (((w4 >> (8 * j)) & 255u) == (uint32_t)o);
                    c += win ? 1u : 0u;
                    bool post = (fwl[k * 64 + q2 * 4 + j] < t) && !win;
                    u64 bit = 1ull << bl;
                    if (win)  wacc |= bit;
                    if (post) pacc |= bit;
                }
            }
            wbA[k] = wacc; pbA[k] = pacc;
        }
        size_t base = (size_t)(t * OO + o) * 4;
        #pragma unroll
        for (int k = 0; k < 4; ++k) {
            winbits[base + k] = wbA[k];
            postbits[base + k] = pbA[k];
        }
        cnt[t * OO + o] = c;
    }
}

// K3: fused popc + chains + prior, LDS-ring pipelined.
// Each bitB row slice / win / post / cnt row is loaded ONCE per block into a
// 16-slot LDS ring via global_load_lds, issued D=6 t-steps ahead. Raw s_barrier
// with COUNTED s_waitcnt vmcnt(4) (guarantees slots <= t+1 resident without
// draining the pipeline — __syncthreads would vmcnt(0) every iteration).
// Window threads (tid<128) OR 11 ring slots (LDS, not global) into pot/ltp;
// chains (all 320) consume via double-buffered potL/ltpL. One barrier per t.
#define PBLK 16
#define OBLK 20
#define FTHR 320
#define ROWSTRIDE (4 * INN)   // u64 elements per t-row of bitB
#define PFD 6                 // prefetch distance (slots)
#define RS 16                 // ring slots; RS >= PFD + 10

__global__ __launch_bounds__(FTHR) void k_fused(
        const float* __restrict__ L0,
        const float* __restrict__ p0arr,
        const u64* __restrict__ bitB,
        const u64* __restrict__ winbits,
        const u64* __restrict__ postbits,
        const uint32_t* __restrict__ cnt,
        float* __restrict__ outL,
        float* __restrict__ outp) {
    // ---- prior chain: single extra block ----
    if (blockIdx.x == 49) {
        if (blockIdx.y != 0) return;
        int l = threadIdx.x;
        if (l >= 64) return;
        bool has2 = (l + 64) < OO;
        float pa = p0arr[l];
        float pb = has2 ? p0arr[l + 64] : -1e30f;
        auto normalize = [&]() {
            pa = fminf(fmaxf(pa, -5.0f), 0.0f);
            if (has2) pb = fminf(fmaxf(pb, -5.0f), 0.0f);
            float mx = has2 ? fmaxf(pa, pb) : pa;
            #pragma unroll
            for (int s = 32; s > 0; s >>= 1) mx = fmaxf(mx, __shfl_xor(mx, s, 64));
            float sm = expf(pa - mx) + (has2 ? expf(pb - mx) : 0.0f);
            #pragma unroll
            for (int s = 32; s > 0; s >>= 1) sm += __shfl_xor(sm, s, 64);
            float lse = logf(sm) + mx;
            pa -= lse;
            if (has2) pb -= lse;
        };
        normalize();
        for (int t = 0; t < TT; ++t) {
            float eta = 0.001f / (float)(t + 1);
            float wma = (float)cnt[t * OO + l] * (1.0f / 256.0f);
            pa += eta * ((-5.0f * pa - 1.0f) * wma - (1.0f - wma));
            if (has2) {
                float wmb = (float)cnt[t * OO + l + 64] * (1.0f / 256.0f);
                pb += eta * ((-5.0f * pb - 1.0f) * wmb - (1.0f - wmb));
            }
            normalize();
        }
        outp[l] = pa;
        if (has2) outp[l + 64] = pb;
        return;
    }

    __shared__ __align__(16) u64 rowRing[RS][128];     // [slot][k*16+pl]
    __shared__ __align__(16) u64 winRing[RS][80];      // [slot][ol*4+j]
    __shared__ __align__(16) u64 postRing[RS][80];
    __shared__ __align__(16) uint32_t cntRing[RS][20];
    __shared__ __align__(16) u64 potL[2][16][10];      // [buf][pl][k], pad->80B stride
    __shared__ __align__(16) u64 ltpL[2][16][10];

    int tid = threadIdx.x;
    int wave = tid >> 6;
    int lane = tid & 63;
    int p0 = blockIdx.x * PBLK;     // 0..48
    int o0 = blockIdx.y * OBLK;     // 0..4

    // chain ids
    int pl = tid & 15;
    int ol = tid >> 4;              // 0..19
    int o  = o0 + ol;
    int i0 = p0 + pl;
    int i1 = i0 + PAIRS;

    // wave0 row-loader: lane -> u64 pair (2*lane, 2*lane+1) of the 128-elem slice
    //   elem index e = k*16 + plq : k = lane>>3, plq = (lane&7)*2
    //   global col  = (k&3)*INN + (k>>2)*PAIRS + p0 + plq   (plq,plq+1 consecutive)
    int lk  = lane >> 3;
    int lpq = (lane & 7) * 2;
    const u64* rowsrc = bitB + (size_t)((lk & 3) * INN + (lk >> 2) * PAIRS + p0 + lpq);

    // window thread mapping (tid < 128): wpl = tid&15, wk = tid>>4 (0..7)
    int wpl = tid & 15;
    int wk  = tid >> 4;
    int eidx = wk * 16 + wpl;

    auto issue = [&](int s) {
        int rr = (s < TT) ? s : (TT - 1);
        int slot = s & (RS - 1);
        if (wave == 0) {
            GLD16(rowsrc + (size_t)rr * ROWSTRIDE, &rowRing[slot][2 * lane]);
        } else if (wave == 1) {
            if (lane < 40)
                GLD16(winbits + ((size_t)rr * OO + o0) * 4 + 2 * lane,
                      &winRing[slot][2 * lane]);
        } else if (wave == 2) {
            if (lane < 40)
                GLD16(postbits + ((size_t)rr * OO + o0) * 4 + 2 * lane,
                      &postRing[slot][2 * lane]);
        } else if (wave == 3) {
            if (lane < 5)
                GLD16(cnt + ((size_t)rr * OO + o0) + 4 * lane,
                      &cntRing[slot][4 * lane]);
        }
    };

    // ---- prologue: fill slots 0..PFD-1, build t=0 pot/ltp, init chains ----
    for (int s = 0; s < PFD; ++s) issue(s);
    if (wave < 4) asm volatile("s_waitcnt vmcnt(0)" ::: "memory");
    __builtin_amdgcn_s_barrier();
    if (tid < 128) {
        u64 r0 = rowRing[0][eidx];      // rows -10..0 all clamp to row 0
        potL[0][wpl][wk] = r0;
        ltpL[0][wpl][wk] = r0;
    }
    float a  = L0[(size_t)i0 * OO + o];
    float b2 = L0[(size_t)i1 * OO + o];
    a  = fminf(fmaxf(a,  -5.0f), 0.0f);
    b2 = fminf(fmaxf(b2, -5.0f), 0.0f);
    {
        float m = fmaxf(a, b2), mn = fminf(a, b2);
        float lse = __logf(1.0f + __expf(mn - m)) + m;
        a -= lse; b2 -= lse;
    }
    asm volatile("s_waitcnt lgkmcnt(0)" ::: "memory");
    __builtin_amdgcn_s_barrier();

    for (int t = 0; t < TT; ++t) {
        int cur = t & 1, nxt = cur ^ 1;
        issue(t + PFD);                 // async, lands slots ahead
        int st = t & (RS - 1);
        // -- chain update from buf[cur] + ring slot t --
        u64 W0 = winRing[st][ol * 4 + 0], W1 = winRing[st][ol * 4 + 1];
        u64 W2 = winRing[st][ol * 4 + 2], W3 = winRing[st][ol * 4 + 3];
        u64 S0 = postRing[st][ol * 4 + 0], S1 = postRing[st][ol * 4 + 1];
        u64 S2 = postRing[st][ol * 4 + 2], S3 = postRing[st][ol * 4 + 3];
        const u64* Pp = potL[cur][pl];
        const u64* Lp = ltpL[cur][pl];
        uint32_t lt0 = __popcll(Lp[0] & W0) + __popcll(Lp[1] & W1)
                     + __popcll(Lp[2] & W2) + __popcll(Lp[3] & W3);
        uint32_t lt1 = __popcll(Lp[4] & W0) + __popcll(Lp[5] & W1)
                     + __popcll(Lp[6] & W2) + __popcll(Lp[7] & W3);
        uint32_t pp0 = __popcll(Pp[0] & S0) + __popcll(Pp[1] & S1)
                     + __popcll(Pp[2] & S2) + __popcll(Pp[3] & S3);
        uint32_t pp1 = __popcll(Pp[4] & S0) + __popcll(Pp[5] & S1)
                     + __popcll(Pp[6] & S2) + __popcll(Pp[7] & S3);
        float cwin = (float)cntRing[st][ol];
        float lt0f = (float)lt0, lt1f = (float)lt1;
        float pp0f = (float)pp0, pp1f = (float)pp1;
        float eta = 0.001f / (float)(t + 1);
        float dw0 = (5.0f * __expf(-a)  - 1.0f) * (lt0f * (1.0f/256.0f))
                  + (cwin - lt0f - pp0f) * (1.0f/256.0f);
        float dw1 = (5.0f * __expf(-b2) - 1.0f) * (lt1f * (1.0f/256.0f))
                  + (cwin - lt1f - pp1f) * (1.0f/256.0f);
        a  += eta * dw0;
        b2 += eta * dw1;
        a  = fminf(fmaxf(a,  -5.0f), 0.0f);
        b2 = fminf(fmaxf(b2, -5.0f), 0.0f);
        float m = fmaxf(a, b2), mn = fminf(a, b2);
        float lse = __logf(1.0f + __expf(mn - m)) + m;
        a -= lse; b2 -= lse;
        // -- window for t+1 from ring (pure LDS) --
        if (tid < 128) {
            int rbase = t + 1 - 10;
            u64 acc = 0;
            #pragma unroll
            for (int j = 1; j <= 10; ++j) {
                int rr = rbase + j; if (rr < 0) rr = 0;
                acc |= rowRing[rr & (RS - 1)][eidx];
            }
            int rz = (rbase < 0) ? 0 : rbase;
            u64 lt = acc | rowRing[rz & (RS - 1)][eidx];
            potL[nxt][wpl][wk] = acc;
            ltpL[nxt][wpl][wk] = lt;
        }
        // -- end-of-iter: counted vmcnt (slots <= t+2 resident), publish LDS --
        if (wave < 4) {
            asm volatile("s_waitcnt vmcnt(4) lgkmcnt(0)" ::: "memory");
        } else {
            asm volatile("s_waitcnt lgkmcnt(0)" ::: "memory");
        }
        __builtin_amdgcn_s_barrier();
    }
    outL[(size_t)i0 * OO + o] = a;
    outL[(size_t)i1 * OO + o] = b2;
}

extern "C" void kernel_launch(void* const* d_in, const int* in_sizes, int n_in,
                              void* d_out, int out_size, void* d_ws, size_t ws_size,
                              hipStream_t stream) {
    const int*   x  = (const int*)d_in[0];
    const float* L0 = (const float*)d_in[1];
    const float* p0 = (const float*)d_in[2];
    float* out = (float*)d_out;

    char* ws = (char*)d_ws;
    size_t off = 0;
    auto alloc = [&](size_t bytes) -> void* {
        off = (off + 255) & ~(size_t)255;
        void* p = ws + off;
        off += bytes;
        return p;
    };
    uint8_t*  widx     = (uint8_t*) alloc((size_t)TT * BB);
    uint32_t* cnt      = (uint32_t*)alloc((size_t)TT * OO * 4);
    u64*      winbits  = (u64*)     alloc((size_t)TT * OO * 4 * 8);
    u64*      postbits = (u64*)     alloc((size_t)TT * OO * 4 * 8);
    u64*      bitB     = (u64*)     alloc((size_t)TT * 4 * INN * 8);
    (void)ws_size;

    hipLaunchKernelGGL(k_winbit, dim3(600), dim3(256), 0, stream, x, widx, bitB);
    hipLaunchKernelGGL(k_fwpost, dim3(OO), dim3(256), 0, stream,
                       widx, winbits, postbits, cnt);
    hipLaunchKernelGGL(k_fused, dim3(50, 5), dim3(FTHR), 0, stream,
                       L0, p0, bitB, winbits, postbits, cnt,
                       out, out + (size_t)INN * OO);
}